// Round 3
// baseline (184.509 us; speedup 1.0000x reference)
//
#include <hip/hip_runtime.h>

// Problem constants (match reference): B=8192, P=32, D=128, V=100000
#define BB 8192
#define PP 32
#define DD 128
#define NBLK (BB / 4)   // 2048 blocks, exact-fit 8/CU

// One wave per batch row (verified-best mapping); block = 4 waves;
// grid = 2048 (8 blocks/CU, exact-fit: 16.6 KB LDS, <=64 VGPR -> 32
// waves/CU). Each pair's 512B embed row is loaded by a full 32-lane
// HALF-WAVE as one float4/lane instruction -> 8 distinct 64B lines per
// pair (minimum line-lookups, ~1.1M total). Halves process interleaved
// pairs pid = 2j+h so exec masks stay near-full for any len.
//
// NEW vs round-2: the finalize kernel is FUSED via last-block-done,
// removing one dispatch + one launch gap (~3 us structural cost).
// The workspace counter needs no init despite per-iteration re-poison:
// poison is a uniform fill, so a never-written ws word at the same
// 256B phase (ctrl[64]) holds the counter's exact initial value.
// last = ((add(ctr) - baseline) & 2047) == 2047 is poison-value- and
// replay-count-invariant (modulo wraparound). Release fence before the
// counter add; device-scope atomic loads of partials in the last block.
__global__ __launch_bounds__(256) void hs_loss_kernel(
    const float* __restrict__ hidden,      // [B, D]
    const int*   __restrict__ path,        // [B, P]
    const int*   __restrict__ path_len,    // [B]
    const int*   __restrict__ code,        // [B, P]
    const float* __restrict__ embed,       // [V, D]
    float2*       __restrict__ partials,   // [NBLK] {loss_sum, count} per block
    unsigned int* __restrict__ ctrl,       // ctrl[0]=counter, ctrl[64]=baseline
    float*        __restrict__ out)        // [1]
{
    const int tid = threadIdx.x;
    const int w   = tid >> 6;              // wave in block, 0..3
    const int l   = tid & 63;              // lane
    const int h   = l >> 5;                // half, 0 or 1
    const int hl  = l & 31;                // lane within half
    const int b   = blockIdx.x * 4 + w;    // this wave's batch row

    __shared__ float plds[4][PP * 33];     // 4 wave-private slices, 16.5 KB
    __shared__ float2 bpart[4];
    __shared__ unsigned int s_last;
    float* const myp = plds[w];

    const int len   = path_len[b];         // wave-uniform
    const int idx_l = path[b * PP + hl];   // lane hl holds pair hl's index
    const int cd_l  = code[b * PP + hl];   // (both halves duplicate)

    // lane's 16B slice of the hidden row (both halves identical -> L1 hit)
    const float4 hv = ((const float4*)(hidden + (size_t)b * DD))[hl];

    // ---- phase 1: batched full-row loads + partial dots ----
    #pragma unroll
    for (int batch = 0; batch < 4; ++batch) {
        const int p0 = batch * 8;          // this batch covers pids p0..p0+7
        if (p0 < len) {                    // wave-uniform batch skip
            int pid[4];
            float4 e[4];
            #pragma unroll
            for (int j = 0; j < 4; ++j) {
                pid[j] = p0 + 2 * j + h;   // halves interleave pairs
                const int idx = __shfl(idx_l, pid[j]);
                if (pid[j] < len)          // half-uniform exec mask
                    e[j] = ((const float4*)(embed + (size_t)idx * DD))[hl];
            }
            #pragma unroll
            for (int j = 0; j < 4; ++j) {
                if (pid[j] < len) {
                    const float pr = e[j].x * hv.x + e[j].y * hv.y
                                   + e[j].z * hv.z + e[j].w * hv.w;
                    myp[pid[j] * 33 + hl] = pr;
                }
            }
        }
    }

    // ---- phase 2: half-split partial-sum (same-wave LDS, no barrier) ----
    const int lp = l & 31;                 // pair this lane reduces
    const int kb = h * 16;                 // lanes 0-31: k 0..15; 32-63: 16..31
    float psum = 0.0f;
    #pragma unroll
    for (int k = 0; k < 16; ++k) psum += myp[lp * 33 + kb + k];
    const float dot = psum + __shfl_xor(psum, 32);

    // ---- phase 3: softplus + wave reduction ----
    float loss = 0.0f;
    if (l < 32 && lp < len) {
        // loss = softplus(code ? -dot : dot), stable BCE form
        const float z = cd_l ? -dot : dot;
        loss = fmaxf(z, 0.0f) + __logf(1.0f + __expf(-fabsf(z)));
    }
    #pragma unroll
    for (int m = 1; m <= 32; m <<= 1) loss += __shfl_xor(loss, m);

    // ---- phase 4: block partial + last-block-done election ----
    if (l == 0) bpart[w] = make_float2(loss, (float)len);
    __syncthreads();
    if (tid == 0) {
        float L = 0.0f, C = 0.0f;
        #pragma unroll
        for (int i = 0; i < 4; ++i) { L += bpart[i].x; C += bpart[i].y; }
        partials[blockIdx.x] = make_float2(L, C);
        __threadfence();                   // release: partial visible device-wide
        const unsigned int base =
            __hip_atomic_load(&ctrl[64], __ATOMIC_RELAXED, __HIP_MEMORY_SCOPE_AGENT);
        const unsigned int old =
            __hip_atomic_fetch_add(&ctrl[0], 1u, __ATOMIC_ACQ_REL, __HIP_MEMORY_SCOPE_AGENT);
        s_last = (((old - base) & (NBLK - 1u)) == (NBLK - 1u)) ? 1u : 0u;
    }
    __syncthreads();

    // ---- phase 5: last block reduces all 2048 partials -> out ----
    if (s_last) {
        const unsigned long long* p64 = (const unsigned long long*)partials;
        float ls = 0.0f, cs = 0.0f;
        #pragma unroll
        for (int k = 0; k < NBLK / 256; ++k) {
            // device-scope load: bypasses L1, sees every block's release
            const unsigned long long u = __hip_atomic_load(
                &p64[tid + k * 256], __ATOMIC_RELAXED, __HIP_MEMORY_SCOPE_AGENT);
            union { unsigned long long u; float2 f; } cv;
            cv.u = u;
            ls += cv.f.x;
            cs += cv.f.y;
        }
        #pragma unroll
        for (int m = 1; m <= 32; m <<= 1) {
            ls += __shfl_xor(ls, m);
            cs += __shfl_xor(cs, m);
        }
        __shared__ float s_l[4], s_c[4];
        if (l == 0) { s_l[w] = ls; s_c[w] = cs; }
        __syncthreads();
        if (tid == 0) {
            float L = 0.0f, C = 0.0f;
            #pragma unroll
            for (int wv = 0; wv < 4; ++wv) { L += s_l[wv]; C += s_c[wv]; }
            out[0] = L / C;
        }
    }
}

extern "C" void kernel_launch(void* const* d_in, const int* in_sizes, int n_in,
                              void* d_out, int out_size, void* d_ws, size_t ws_size,
                              hipStream_t stream) {
    const float* hidden   = (const float*)d_in[0];  // [B, D] f32
    // d_in[1] = target (unused by the reference computation)
    const int*   path     = (const int*)d_in[2];    // [B, P]
    const int*   path_len = (const int*)d_in[3];    // [B]
    const int*   code     = (const int*)d_in[4];    // [B, P]
    const float* embed    = (const float*)d_in[5];  // [V, D] f32
    float*  out      = (float*)d_out;

    float2*       partials = (float2*)d_ws;                      // 16 KB
    unsigned int* ctrl     = (unsigned int*)((char*)d_ws + 16384);
    // ctrl[0] = counter (atomically bumped); ctrl[64] = baseline word,
    // never written -> always holds the poison value = counter's initial.

    hs_loss_kernel<<<NBLK, 256, 0, stream>>>(hidden, path, path_len, code,
                                             embed, partials, ctrl, out);
}

// Round 4
// 100.337 us; speedup vs baseline: 1.8389x; 1.8389x over previous
//
#include <hip/hip_runtime.h>

// Problem constants (match reference): B=8192, P=32, D=128, V=100000
#define BB 8192
#define PP 32
#define DD 128

// One wave per batch row; block = 4 waves; grid = 2048 (8 blocks/CU,
// exact-fit: 16.6 KB LDS, <=64 VGPR -> 32 waves/CU). Each pair's 512B
// embed row is loaded by a full 32-lane HALF-WAVE as one float4/lane
// instruction -> 8 distinct 64B lines per pair (minimum line-lookups).
// Halves process interleaved pairs pid = 2j+h so exec masks stay full.
//
// NEW vs round-2: R3's profile exposed VGPR_Count=24 for this kernel --
// proof the compiler FUSED the load/consume loops (1 load in flight per
// wave, latency-serialized gather). Phase 1 now issues 8 pair-loads per
// batch and pins them with sched_barrier(0) so all 8 global_load_dwordx4
// are emitted before any consumption (~50-60 VGPR, still 8 waves/SIMD).
//
// R3's fused-finalize via global atomic counter is REVERTED: 2048
// same-address device-scope atomics serialize at the coherence point
// (~100 us measured). Two-kernel structure restored.
__global__ __launch_bounds__(256) void hs_loss_kernel(
    const float* __restrict__ hidden,      // [B, D]
    const int*   __restrict__ path,        // [B, P]
    const int*   __restrict__ path_len,    // [B]
    const int*   __restrict__ code,        // [B, P]
    const float* __restrict__ embed,       // [V, D]
    float2* __restrict__ partials)         // [2048] {loss_sum, count} per block
{
    const int tid = threadIdx.x;
    const int w   = tid >> 6;              // wave in block, 0..3
    const int l   = tid & 63;              // lane
    const int h   = l >> 5;                // half, 0 or 1
    const int hl  = l & 31;                // lane within half
    const int b   = blockIdx.x * 4 + w;    // this wave's batch row

    __shared__ float plds[4][PP * 33];     // 4 wave-private slices, 16.5 KB
    __shared__ float2 bpart[4];
    float* const myp = plds[w];

    const int len   = path_len[b];         // wave-uniform
    const int idx_l = path[b * PP + hl];   // lane hl holds pair hl's index
    const int cd_l  = code[b * PP + hl];   // (both halves duplicate)

    // lane's 16B slice of the hidden row (both halves identical -> L1 hit)
    const float4 hv = ((const float4*)(hidden + (size_t)b * DD))[hl];

    // ---- phase 1: 8 loads in flight per wave, then consume ----
    #pragma unroll
    for (int batch = 0; batch < 2; ++batch) {
        const int p0 = batch * 16;         // this batch covers pids p0..p0+15
        if (p0 < len) {                    // wave-uniform batch skip
            int pid[8];
            float4 e[8];
            #pragma unroll
            for (int j = 0; j < 8; ++j) {
                pid[j] = p0 + 2 * j + h;   // halves interleave pairs
                const int idx = __shfl(idx_l, pid[j]);
                if (pid[j] < len)          // half-uniform exec mask
                    e[j] = ((const float4*)(embed + (size_t)idx * DD))[hl];
            }
            // Hard scheduling fence: no consume may be hoisted above,
            // no load may sink below -> all 8 loads issued back-to-back.
            __builtin_amdgcn_sched_barrier(0);
            #pragma unroll
            for (int j = 0; j < 8; ++j) {
                if (pid[j] < len) {
                    const float pr = e[j].x * hv.x + e[j].y * hv.y
                                   + e[j].z * hv.z + e[j].w * hv.w;
                    myp[pid[j] * 33 + hl] = pr;
                }
            }
        }
    }

    // ---- phase 2: half-split partial-sum (same-wave LDS, no barrier) ----
    const int lp = l & 31;                 // pair this lane reduces
    const int kb = h * 16;                 // lanes 0-31: k 0..15; 32-63: 16..31
    float psum = 0.0f;
    #pragma unroll
    for (int k = 0; k < 16; ++k) psum += myp[lp * 33 + kb + k];
    const float dot = psum + __shfl_xor(psum, 32);

    // ---- phase 3: softplus + wave reduction ----
    float loss = 0.0f;
    if (l < 32 && lp < len) {
        // loss = softplus(code ? -dot : dot), stable BCE form
        const float z = cd_l ? -dot : dot;
        loss = fmaxf(z, 0.0f) + __logf(1.0f + __expf(-fabsf(z)));
    }
    #pragma unroll
    for (int m = 1; m <= 32; m <<= 1) loss += __shfl_xor(loss, m);

    // ---- phase 4: block pre-reduction -> one float2 per block ----
    if (l == 0) bpart[w] = make_float2(loss, (float)len);
    __syncthreads();
    if (tid == 0) {
        float L = 0.0f, C = 0.0f;
        #pragma unroll
        for (int i = 0; i < 4; ++i) { L += bpart[i].x; C += bpart[i].y; }
        partials[blockIdx.x] = make_float2(L, C);
    }
}

// Single-block reduction of the 2048 block partials (16 KB, float4 loads).
__global__ __launch_bounds__(256) void hs_finalize_kernel(
    const float2* __restrict__ partials, float* __restrict__ out)
{
    const int tid = threadIdx.x;
    const float4* p4 = (const float4*)partials;    // 1024 float4
    float ls = 0.0f, cs = 0.0f;
    #pragma unroll
    for (int k = 0; k < 4; ++k) {
        const float4 v = p4[tid + k * 256];        // {loss,cnt,loss,cnt}
        ls += v.x + v.z;
        cs += v.y + v.w;
    }
    #pragma unroll
    for (int m = 1; m <= 32; m <<= 1) {
        ls += __shfl_xor(ls, m);
        cs += __shfl_xor(cs, m);
    }
    __shared__ float s_l[4], s_c[4];
    const int wave = tid >> 6;
    if ((tid & 63) == 0) { s_l[wave] = ls; s_c[wave] = cs; }
    __syncthreads();
    if (tid == 0) {
        float L = 0.0f, C = 0.0f;
        #pragma unroll
        for (int wv = 0; wv < 4; ++wv) { L += s_l[wv]; C += s_c[wv]; }
        out[0] = L / C;
    }
}

extern "C" void kernel_launch(void* const* d_in, const int* in_sizes, int n_in,
                              void* d_out, int out_size, void* d_ws, size_t ws_size,
                              hipStream_t stream) {
    const float* hidden   = (const float*)d_in[0];  // [B, D] f32
    // d_in[1] = target (unused by the reference computation)
    const int*   path     = (const int*)d_in[2];    // [B, P]
    const int*   path_len = (const int*)d_in[3];    // [B]
    const int*   code     = (const int*)d_in[4];    // [B, P]
    const float* embed    = (const float*)d_in[5];  // [V, D] f32
    float*  out      = (float*)d_out;
    float2* partials = (float2*)d_ws;               // 2048 * 8B = 16 KB

    hs_loss_kernel<<<BB / 4, 256, 0, stream>>>(hidden, path, path_len, code,
                                               embed, partials);
    hs_finalize_kernel<<<1, 256, 0, stream>>>(partials, out);
}